// Round 8
// baseline (237.953 us; speedup 1.0000x reference)
//
#include <hip/hip_runtime.h>
#include <hip/hip_bf16.h>
#include <stdint.h>

#define TOKENS 8192
#define IN_F   4096
#define OUT_F  4096
#define RANK   512

typedef __attribute__((ext_vector_type(8))) __bf16 bf16x8;
typedef __attribute__((ext_vector_type(4))) float f32x4;
typedef __attribute__((ext_vector_type(4))) short short4v;
typedef __attribute__((ext_vector_type(8))) short short8v;
typedef __attribute__((ext_vector_type(4))) int i32x4;

static __device__ __forceinline__ unsigned short f2bf(float f) {
  union { float f; unsigned u; } v; v.f = f;
  return (unsigned short)((v.u + 0x7FFFu + ((v.u >> 16) & 1u)) >> 16);
}
static __device__ __forceinline__ float bf2f(unsigned short us) {
  union { unsigned u; float f; } v; v.u = ((unsigned)us) << 16;
  return v.f;
}

static __device__ __forceinline__ void gload_lds16(const void* g, void* l) {
  __builtin_amdgcn_global_load_lds(
      (const __attribute__((address_space(1))) unsigned*)g,
      (__attribute__((address_space(3))) unsigned*)l, 16, 0, 0);
}

// ---------------------------------------------------------------------------
// prep_bm: build combined weight M (bf16):
//   M[o,i] = q[o,i]*scale + min_val + sum_r U[o,r]*S[r]*V[i,r]
// ---------------------------------------------------------------------------
__global__ __launch_bounds__(256) void prep_bm(
    const float* __restrict__ U, const float* __restrict__ V,
    const float* __restrict__ S, const int* __restrict__ q,
    const float* __restrict__ scale_p, const float* __restrict__ minv_p,
    unsigned short* __restrict__ M) {
  __shared__ unsigned short lA[128 * 64];
  __shared__ unsigned short lB[128 * 64];

  const int bid  = blockIdx.x;  // 0..1023
  const int tid  = threadIdx.x;
  const int wid  = tid >> 6;
  const int lane = tid & 63;
  const int bm = bid >> 5;
  const int bn = bid & 31;
  const int wm = (wid >> 1) * 64;
  const int wn = (wid & 1) * 64;

  f32x4 acc[4][4] = {};

  const int sr = tid >> 4;
  const int sc = (tid & 15) * 4;

  for (int k0 = 0; k0 < RANK; k0 += 64) {
    __syncthreads();
#pragma unroll
    for (int p = 0; p < 8; ++p) {
      int row = p * 16 + sr;
      f32x4 uv = *(const f32x4*)&U[(size_t)(bm * 128 + row) * RANK + k0 + sc];
      short4v pa;
      pa.x = (short)f2bf(uv.x); pa.y = (short)f2bf(uv.y);
      pa.z = (short)f2bf(uv.z); pa.w = (short)f2bf(uv.w);
      *(short4v*)&lA[row * 64 + sc] = pa;
      f32x4 vv = *(const f32x4*)&V[(size_t)(bn * 128 + row) * RANK + k0 + sc];
      f32x4 sv = *(const f32x4*)&S[k0 + sc];
      short4v pb;
      pb.x = (short)f2bf(vv.x * sv.x); pb.y = (short)f2bf(vv.y * sv.y);
      pb.z = (short)f2bf(vv.z * sv.z); pb.w = (short)f2bf(vv.w * sv.w);
      *(short4v*)&lB[row * 64 + sc] = pb;
    }
    __syncthreads();
#pragma unroll
    for (int kk = 0; kk < 2; ++kk) {
      bf16x8 af[4], bfr[4];
#pragma unroll
      for (int m = 0; m < 4; ++m)
        af[m] = *(const bf16x8*)&lA[(wm + m * 16 + (lane & 15)) * 64 + kk * 32 + (lane >> 4) * 8];
#pragma unroll
      for (int n = 0; n < 4; ++n)
        bfr[n] = *(const bf16x8*)&lB[(wn + n * 16 + (lane & 15)) * 64 + kk * 32 + (lane >> 4) * 8];
#pragma unroll
      for (int m = 0; m < 4; ++m)
#pragma unroll
        for (int n = 0; n < 4; ++n)
          acc[m][n] = __builtin_amdgcn_mfma_f32_16x16x32_bf16(af[m], bfr[n], acc[m][n], 0, 0, 0);
    }
  }

  const float scale = *scale_p;
  const float minv  = *minv_p;
  const int o0 = bm * 128 + wm;
  const int i0 = bn * 128 + wn;
#pragma unroll
  for (int m = 0; m < 4; ++m) {
#pragma unroll
    for (int n = 0; n < 4; ++n) {
      int col = i0 + n * 16 + (lane & 15);
#pragma unroll
      for (int rr = 0; rr < 4; ++rr) {
        int row = o0 + m * 16 + (lane >> 4) * 4 + rr;
        float dq = (float)q[(size_t)row * IN_F + col] * scale + minv;
        M[(size_t)row * IN_F + col] = f2bf(acc[m][n][rr] + dq);
      }
    }
  }
}

// ---------------------------------------------------------------------------
// prep_q: blocks [0,8192): per-token i8 quant of x (f32 rows);
//         blocks [8192,12288): per-row i8 quant of M (bf16 rows).
// Fused so the two memory streams overlap.
// ---------------------------------------------------------------------------
__global__ __launch_bounds__(256) void prep_q(
    const float* __restrict__ x, char* __restrict__ xi8, float* __restrict__ sx,
    const unsigned short* __restrict__ M, char* __restrict__ mi8,
    float* __restrict__ sm) {
  __shared__ float red[4];
  const int t = threadIdx.x;
  float v[16];
  float am = 0.f;

  if (blockIdx.x < 8192) {
    const int row = blockIdx.x;
    const float* xr = x + (size_t)row * IN_F;
#pragma unroll
    for (int j = 0; j < 4; ++j) {
      f32x4 f = *(const f32x4*)&xr[t * 16 + j * 4];
#pragma unroll
      for (int e = 0; e < 4; ++e) {
        v[j * 4 + e] = f[e];
        am = fmaxf(am, fabsf(f[e]));
      }
    }
#pragma unroll
    for (int s = 32; s; s >>= 1) am = fmaxf(am, __shfl_xor(am, s));
    if ((t & 63) == 0) red[t >> 6] = am;
    __syncthreads();
    am = fmaxf(fmaxf(red[0], red[1]), fmaxf(red[2], red[3]));
    am = fmaxf(am, 1e-12f);
    const float inv = 127.0f / am;
    i32x4 pk;
#pragma unroll
    for (int j = 0; j < 4; ++j) {
      unsigned p = 0;
#pragma unroll
      for (int e = 0; e < 4; ++e) {
        float qf = rintf(v[j * 4 + e] * inv);
        qf = fminf(fmaxf(qf, -127.f), 127.f);
        p |= ((unsigned)((int)qf & 0xFF)) << (8 * e);
      }
      pk[j] = (int)p;
    }
    *(i32x4*)&xi8[(size_t)row * IN_F + t * 16] = pk;
    if (t == 0) sx[row] = am * (1.0f / 127.0f);
  } else {
    const int row = blockIdx.x - 8192;
    const unsigned short* mr = M + (size_t)row * IN_F;
#pragma unroll
    for (int j = 0; j < 2; ++j) {
      short8v h = *(const short8v*)&mr[t * 16 + j * 8];
#pragma unroll
      for (int e = 0; e < 8; ++e) {
        float f = bf2f((unsigned short)h[e]);
        v[j * 8 + e] = f;
        am = fmaxf(am, fabsf(f));
      }
    }
#pragma unroll
    for (int s = 32; s; s >>= 1) am = fmaxf(am, __shfl_xor(am, s));
    if ((t & 63) == 0) red[t >> 6] = am;
    __syncthreads();
    am = fmaxf(fmaxf(red[0], red[1]), fmaxf(red[2], red[3]));
    am = fmaxf(am, 1e-12f);
    const float inv = 127.0f / am;
    i32x4 pk;
#pragma unroll
    for (int j = 0; j < 4; ++j) {
      unsigned p = 0;
#pragma unroll
      for (int e = 0; e < 4; ++e) {
        float qf = rintf(v[j * 4 + e] * inv);
        qf = fminf(fmaxf(qf, -127.f), 127.f);
        p |= ((unsigned)((int)qf & 0xFF)) << (8 * e);
      }
      pk[j] = (int)p;
    }
    *(i32x4*)&mi8[(size_t)row * IN_F + t * 16] = pk;
    if (t == 0) sm[row] = am * (1.0f / 127.0f);
  }
}

// ---------------------------------------------------------------------------
// helpers for gemm256_i8
// ---------------------------------------------------------------------------
static __device__ __forceinline__ void readA4i(i32x4 (&a)[4][2],
                                               const char* __restrict__ base,
                                               const int (&off)[4][2]) {
#pragma unroll
  for (int m = 0; m < 4; ++m)
#pragma unroll
    for (int kk = 0; kk < 2; ++kk)
      a[m][kk] = *(const i32x4*)(base + off[m][kk]);
}
static __device__ __forceinline__ void readB2i(i32x4 (&b)[2][2],
                                               const char* __restrict__ base,
                                               const int (&off)[2][2]) {
#pragma unroll
  for (int n = 0; n < 2; ++n)
#pragma unroll
    for (int kk = 0; kk < 2; ++kk)
      b[n][kk] = *(const i32x4*)(base + off[n][kk]);
}
static __device__ __forceinline__ void mfmaQi(i32x4 (&aq)[4][2],
                                              const i32x4 (&a)[4][2],
                                              const i32x4 (&b)[2][2]) {
#pragma unroll
  for (int m = 0; m < 4; ++m)
#pragma unroll
    for (int n = 0; n < 2; ++n)
#pragma unroll
      for (int kk = 0; kk < 2; ++kk)
        aq[m][n] = __builtin_amdgcn_mfma_i32_16x16x64_i8(a[m][kk], b[n][kk],
                                                         aq[m][n], 0, 0, 0);
}

#define BARR()  __builtin_amdgcn_s_barrier()
#define SCHED() __builtin_amdgcn_sched_barrier(0)
#define LGKM0() asm volatile("s_waitcnt lgkmcnt(0)")
#define PRIO1() __builtin_amdgcn_s_setprio(1)
#define PRIO0() __builtin_amdgcn_s_setprio(0)

// ---------------------------------------------------------------------------
// gemm256_i8: out[t,o] = sx[t]*sm[o] * sum_i xi8[t,i]*mi8[o,i]
// 256x256 tile, K-tile = 128 i8, TWO phases per K-tile (4 barriers, was 8):
//   ph1: read {A0, B0, B1}; stage (t+1).A1;              MFMA Q00+Q01 (32)
//   ph2: read {A1};        stage (t+2).{A0,B0,B1}; vmcnt(6); MFMA Q11+Q10 (32)
// Overwrite safety: (t+1).A1 -> other buf (last read ph2 of t-1, barrier ago);
// (t+2).{A0,B0,B1} overwrite regions whose reads all completed at ph1's
// closing barrier. vmcnt(6) at ph2 end retires exactly tile (t+1)'s 8 loads
// (in-flight 14 -> 6). Integer accumulation => bit-identical to round 7.
// ---------------------------------------------------------------------------
__global__ __launch_bounds__(512, 2) void gemm256_i8(
    const char* __restrict__ xi8, const char* __restrict__ mi8,
    const float* __restrict__ sx, const float* __restrict__ sm,
    float* __restrict__ out) {
  extern __shared__ __align__(128) char smem[];
  const int tid  = threadIdx.x;
  const int wid  = tid >> 6;
  const int lane = tid & 63;
  const int wqm  = wid >> 2;
  const int wqn  = wid & 3;

  const int swz = (blockIdx.x & 7) * 64 + (blockIdx.x >> 3);
  const int bm = swz >> 4;
  const int bn = swz & 15;
  const int row0 = bm * 256;
  const int col0 = bn * 256;

  int offA[4][2], offB[2][2];
#pragma unroll
  for (int m = 0; m < 4; ++m)
#pragma unroll
    for (int kk = 0; kk < 2; ++kk) {
      int r = wqm * 64 + m * 16 + (lane & 15);
      int cb = kk * 64 + (lane >> 4) * 16;
      offA[m][kk] = r * 128 + (cb ^ ((r & 7) << 4));
    }
#pragma unroll
  for (int n = 0; n < 2; ++n)
#pragma unroll
    for (int kk = 0; kk < 2; ++kk) {
      int r = wqn * 32 + n * 16 + (lane & 15);
      int cb = kk * 64 + (lane >> 4) * 16;
      offB[n][kk] = r * 128 + (cb ^ ((r & 7) << 4));
    }

  const int sco = (((lane & 7) ^ (lane >> 3)) << 4);
  const int srw = lane >> 3;
  const char* aP = xi8 + (size_t)(row0 + wid * 16 + srw) * IN_F + sco;
  const char* bP = mi8 + (size_t)(col0 + wid * 16 + srw) * IN_F + sco;
  const char* aH = aP + (size_t)128 * IN_F;
  const char* bH = bP + (size_t)128 * IN_F;
  char* lw = smem + wid * 2048;

  auto STG = [&](const char* __restrict__ g, char* l) {
    gload_lds16(g, l);
    gload_lds16(g + 8 * IN_F, l + 1024);
  };

  i32x4 acc[4][4][2] = {};
  i32x4 a[4][2], b0[2][2], b1[2][2];

  // ---- prologue: t0 {A0,B0,B1,A1} -> buf0; t1 {A0,B0,B1} -> buf1 ----
  STG(aP,        lw + 0);
  STG(bP,        lw + 32768);
  STG(bH,        lw + 49152);
  STG(aH,        lw + 16384);
  STG(aP + 128,  lw + 65536);
  STG(bP + 128,  lw + 98304);
  STG(bH + 128,  lw + 114688);
  asm volatile("s_waitcnt vmcnt(6)");
  SCHED();
  BARR();

  // ---- main loop: 15 iterations, tiles 0..29 ----
  for (int it = 0; it < 15; ++it) {
    // ===== tile tt (buf0) =====
    // ph1
    readA4i(a, smem, offA);
    readB2i(b0, smem + 32768, offB);
    readB2i(b1, smem + 49152, offB);
    STG(aH + 128, lw + 81920);                // (tt+1).A1 -> buf1.A1
    BARR(); LGKM0(); SCHED();
    PRIO1(); mfmaQi(acc[0], a, b0); mfmaQi(acc[1], a, b1); PRIO0();
    SCHED(); BARR();
    // ph2
    readA4i(a, smem + 16384, offA);
    STG(aP + 256, lw + 0);                    // (tt+2).A0 -> buf0.A0
    STG(bP + 256, lw + 32768);                // (tt+2).B0 -> buf0.B0
    STG(bH + 256, lw + 49152);                // (tt+2).B1 -> buf0.B1
    asm volatile("s_waitcnt vmcnt(6)");       // (tt+1) fully landed
    BARR(); LGKM0(); SCHED();
    PRIO1(); mfmaQi(acc[2], a, b1); mfmaQi(acc[3], a, b0); PRIO0();
    SCHED(); BARR();

    // ===== tile tt+1 (buf1) =====
    // ph1
    readA4i(a, smem + 65536, offA);
    readB2i(b0, smem + 98304, offB);
    readB2i(b1, smem + 114688, offB);
    STG(aH + 256, lw + 16384);                // (tt+2).A1 -> buf0.A1
    BARR(); LGKM0(); SCHED();
    PRIO1(); mfmaQi(acc[0], a, b0); mfmaQi(acc[1], a, b1); PRIO0();
    SCHED(); BARR();
    // ph2
    readA4i(a, smem + 81920, offA);
    STG(aP + 384, lw + 65536);                // (tt+3).A0 -> buf1.A0
    STG(bP + 384, lw + 98304);                // (tt+3).B0 -> buf1.B0
    STG(bH + 384, lw + 114688);               // (tt+3).B1 -> buf1.B1
    asm volatile("s_waitcnt vmcnt(6)");       // (tt+2) fully landed
    BARR(); LGKM0(); SCHED();
    PRIO1(); mfmaQi(acc[2], a, b1); mfmaQi(acc[3], a, b0); PRIO0();
    SCHED(); BARR();

    aP += 256; bP += 256; aH += 256; bH += 256;
  }

  // ---- peeled tail: tile 30 (buf0), tile 31 (buf1) ----
  // tile 30, ph1
  readA4i(a, smem, offA);
  readB2i(b0, smem + 32768, offB);
  readB2i(b1, smem + 49152, offB);
  STG(aH + 128, lw + 81920);                  // 31.A1 -> buf1.A1
  BARR(); LGKM0(); SCHED();
  PRIO1(); mfmaQi(acc[0], a, b0); mfmaQi(acc[1], a, b1); PRIO0();
  SCHED(); BARR();
  // tile 30, ph2 (no staging; drain everything for tile 31)
  readA4i(a, smem + 16384, offA);
  asm volatile("s_waitcnt vmcnt(0)");
  BARR(); LGKM0(); SCHED();
  PRIO1(); mfmaQi(acc[2], a, b1); mfmaQi(acc[3], a, b0); PRIO0();
  SCHED(); BARR();

  // tile 31 (no staging, no cross-wave hazards -> no barriers)
  readA4i(a, smem + 65536, offA);
  readB2i(b0, smem + 98304, offB);
  readB2i(b1, smem + 114688, offB);
  LGKM0(); SCHED();
  mfmaQi(acc[0], a, b0); mfmaQi(acc[1], a, b1);
  readA4i(a, smem + 81920, offA);
  LGKM0(); SCHED();
  mfmaQi(acc[2], a, b1); mfmaQi(acc[3], a, b0);

  // ---- epilogue: scale by sx[row]*sm[col] ----
  const int qm_[4] = {0, 0, 1, 1};
  const int qn_[4] = {0, 1, 1, 0};
#pragma unroll
  for (int q = 0; q < 4; ++q) {
#pragma unroll
    for (int m = 0; m < 4; ++m) {
#pragma unroll
      for (int n = 0; n < 2; ++n) {
        int col = col0 + qn_[q] * 128 + wqn * 32 + n * 16 + (lane & 15);
        float smv = sm[col];
#pragma unroll
        for (int rr = 0; rr < 4; ++rr) {
          int row = row0 + qm_[q] * 128 + wqm * 64 + m * 16 + (lane >> 4) * 4 + rr;
          out[(size_t)row * OUT_F + col] =
              (float)acc[q][m][n][rr] * sx[row] * smv;
        }
      }
    }
  }
}

// ---------------------------------------------------------------------------
// Fallback main GEMM (128^2, used only if ws too small): A reg-staged from f32.
// ---------------------------------------------------------------------------
__global__ __launch_bounds__(256) void gemm_main_f(const float* __restrict__ xf,
                                                   const unsigned short* __restrict__ Mw,
                                                   float* __restrict__ out) {
  __shared__ unsigned short lA[128 * 64];
  __shared__ unsigned short lB[128 * 64];
  const int tid  = threadIdx.x;
  const int wid  = tid >> 6;
  const int lane = tid & 63;
  const int nwg = gridDim.x;
  const int cpx = nwg >> 3;
  const int swz = (blockIdx.x & 7) * cpx + (blockIdx.x >> 3);
  const int bm = swz >> 5;
  const int bn = swz & 31;
  const int wm = (wid >> 1) * 64;
  const int wn = (wid & 1) * 64;
  const int row0 = bm * 128;
  const int col0 = bn * 128;

  f32x4 acc[4][4] = {};

  for (int k0 = 0; k0 < IN_F; k0 += 64) {
    __syncthreads();
    const int sr = tid >> 4;
    const int sc = (tid & 15) * 4;
#pragma unroll
    for (int p = 0; p < 8; ++p) {
      int row = p * 16 + sr;
      f32x4 v = *(const f32x4*)&xf[(size_t)(row0 + row) * IN_F + k0 + sc];
      short4v pa;
      pa.x = (short)f2bf(v.x); pa.y = (short)f2bf(v.y);
      pa.z = (short)f2bf(v.z); pa.w = (short)f2bf(v.w);
      *(short4v*)&lA[row * 64 + sc] = pa;
    }
#pragma unroll
    for (int j = 0; j < 4; ++j) {
      int rbase = (wid * 4 + j) * 8;
      const unsigned short* src =
          &Mw[(size_t)(col0 + rbase + (lane >> 3)) * IN_F + k0 + (lane & 7) * 8];
      gload_lds16(src, &lB[rbase * 64]);
    }
    __syncthreads();
#pragma unroll
    for (int kk = 0; kk < 2; ++kk) {
      bf16x8 af[4], bfr[4];
#pragma unroll
      for (int m = 0; m < 4; ++m)
        af[m] = *(const bf16x8*)&lA[(wm + m * 16 + (lane & 15)) * 64 + kk * 32 + (lane >> 4) * 8];
#pragma unroll
      for (int n = 0; n < 4; ++n)
        bfr[n] = *(const bf16x8*)&lB[(wn + n * 16 + (lane & 15)) * 64 + kk * 32 + (lane >> 4) * 8];
#pragma unroll
      for (int m = 0; m < 4; ++m)
#pragma unroll
        for (int n = 0; n < 4; ++n)
          acc[m][n] = __builtin_amdgcn_mfma_f32_16x16x32_bf16(af[m], bfr[n], acc[m][n], 0, 0, 0);
    }
  }

#pragma unroll
  for (int m = 0; m < 4; ++m) {
#pragma unroll
    for (int n = 0; n < 4; ++n) {
      int col = col0 + wn + n * 16 + (lane & 15);
#pragma unroll
      for (int rr = 0; rr < 4; ++rr) {
        int row = row0 + wm + m * 16 + (lane >> 4) * 4 + rr;
        out[(size_t)row * OUT_F + col] = acc[m][n][rr];
      }
    }
  }
}

// ---------------------------------------------------------------------------
extern "C" void kernel_launch(void* const* d_in, const int* in_sizes, int n_in,
                              void* d_out, int out_size, void* d_ws, size_t ws_size,
                              hipStream_t stream) {
  const float* x      = (const float*)d_in[0];
  const int*   q      = (const int*)d_in[1];
  const float* scale  = (const float*)d_in[2];
  const float* minv   = (const float*)d_in[3];
  const float* U      = (const float*)d_in[4];
  const float* S      = (const float*)d_in[5];
  const float* V      = (const float*)d_in[6];
  float* out = (float*)d_out;

  const size_t MB32 = 33554432ull;
  unsigned short* Mw = (unsigned short*)d_ws;                    // 32 MB bf16
  char*  xi8 = (char*)d_ws + MB32;                               // 32 MB
  char*  mi8 = (char*)d_ws + 2 * MB32;                           // 16 MB
  float* sx  = (float*)((char*)d_ws + 2 * MB32 + 16777216);      // 32 KB
  float* sm  = (float*)((char*)d_ws + 2 * MB32 + 16777216 + 32768);  // 16 KB
  const size_t need = 2 * MB32 + 16777216 + 32768 + 16384;

  if (ws_size >= need) {
    (void)hipFuncSetAttribute((const void*)gemm256_i8,
                              hipFuncAttributeMaxDynamicSharedMemorySize,
                              131072);
    prep_bm<<<dim3(1024), dim3(256), 0, stream>>>(U, V, S, q, scale, minv, Mw);
    prep_q<<<dim3(12288), dim3(256), 0, stream>>>(x, xi8, sx, Mw, mi8, sm);
    gemm256_i8<<<dim3(512), dim3(512), 131072, stream>>>(xi8, mi8, sx, sm, out);
  } else {
    prep_bm<<<dim3(1024), dim3(256), 0, stream>>>(U, V, S, q, scale, minv, Mw);
    gemm_main_f<<<dim3(2048), dim3(256), 0, stream>>>(x, Mw, out);
  }
}

// Round 9
// 222.200 us; speedup vs baseline: 1.0709x; 1.0709x over previous
//
#include <hip/hip_runtime.h>
#include <hip/hip_bf16.h>
#include <stdint.h>

#define TOKENS 8192
#define IN_F   4096
#define OUT_F  4096
#define RANK   512

typedef __attribute__((ext_vector_type(8))) __bf16 bf16x8;
typedef __attribute__((ext_vector_type(4))) float f32x4;
typedef __attribute__((ext_vector_type(4))) short short4v;
typedef __attribute__((ext_vector_type(8))) short short8v;
typedef __attribute__((ext_vector_type(4))) int i32x4;

static __device__ __forceinline__ unsigned short f2bf(float f) {
  union { float f; unsigned u; } v; v.f = f;
  return (unsigned short)((v.u + 0x7FFFu + ((v.u >> 16) & 1u)) >> 16);
}
static __device__ __forceinline__ float bf2f(unsigned short us) {
  union { unsigned u; float f; } v; v.u = ((unsigned)us) << 16;
  return v.f;
}

static __device__ __forceinline__ void gload_lds16(const void* g, void* l) {
  __builtin_amdgcn_global_load_lds(
      (const __attribute__((address_space(1))) unsigned*)g,
      (__attribute__((address_space(3))) unsigned*)l, 16, 0, 0);
}

#define BARR()  __builtin_amdgcn_s_barrier()
#define SCHED() __builtin_amdgcn_sched_barrier(0)
#define LGKM0() asm volatile("s_waitcnt lgkmcnt(0)")
#define PRIO1() __builtin_amdgcn_s_setprio(1)
#define PRIO0() __builtin_amdgcn_s_setprio(0)

// ---------------------------------------------------------------------------
// prep_conv: blocks [0,8192): per-token i8 quant of x;
//            blocks [8192,8448): U f32->bf16; [8448,8704): (V*S) f32->bf16.
// ---------------------------------------------------------------------------
__global__ __launch_bounds__(256) void prep_conv(
    const float* __restrict__ x, char* __restrict__ xi8, float* __restrict__ sx,
    const float* __restrict__ U, const float* __restrict__ V,
    const float* __restrict__ S,
    unsigned short* __restrict__ Ub, unsigned short* __restrict__ Vs) {
  __shared__ float red[4];
  const int t = threadIdx.x;

  if (blockIdx.x < 8192) {
    const int row = blockIdx.x;
    const float* xr = x + (size_t)row * IN_F;
    float v[16];
    float am = 0.f;
#pragma unroll
    for (int j = 0; j < 4; ++j) {
      f32x4 f = *(const f32x4*)&xr[t * 16 + j * 4];
#pragma unroll
      for (int e = 0; e < 4; ++e) {
        v[j * 4 + e] = f[e];
        am = fmaxf(am, fabsf(f[e]));
      }
    }
#pragma unroll
    for (int s = 32; s; s >>= 1) am = fmaxf(am, __shfl_xor(am, s));
    if ((t & 63) == 0) red[t >> 6] = am;
    __syncthreads();
    am = fmaxf(fmaxf(red[0], red[1]), fmaxf(red[2], red[3]));
    am = fmaxf(am, 1e-12f);
    const float inv = 127.0f / am;
    i32x4 pk;
#pragma unroll
    for (int j = 0; j < 4; ++j) {
      unsigned p = 0;
#pragma unroll
      for (int e = 0; e < 4; ++e) {
        float qf = rintf(v[j * 4 + e] * inv);
        qf = fminf(fmaxf(qf, -127.f), 127.f);
        p |= ((unsigned)((int)qf & 0xFF)) << (8 * e);
      }
      pk[j] = (int)p;
    }
    *(i32x4*)&xi8[(size_t)row * IN_F + t * 16] = pk;
    if (t == 0) sx[row] = am * (1.0f / 127.0f);
    return;
  }

  int b = blockIdx.x - 8192;
  const int nchunk = OUT_F * RANK / 4;  // 524288 f32x4 chunks
  if (b < 256) {
    for (int c = b * 256 + t; c < nchunk; c += 65536) {
      f32x4 v = ((const f32x4*)U)[c];
      short4v o;
      o.x = (short)f2bf(v.x); o.y = (short)f2bf(v.y);
      o.z = (short)f2bf(v.z); o.w = (short)f2bf(v.w);
      ((short4v*)Ub)[c] = o;
    }
  } else {
    b -= 256;
    for (int c = b * 256 + t; c < nchunk; c += 65536) {
      f32x4 v = ((const f32x4*)V)[c];
      f32x4 s = *(const f32x4*)&S[(c * 4) & (RANK - 1)];
      short4v o;
      o.x = (short)f2bf(v.x * s.x); o.y = (short)f2bf(v.y * s.y);
      o.z = (short)f2bf(v.z * s.z); o.w = (short)f2bf(v.w * s.w);
      ((short4v*)Vs)[c] = o;
    }
  }
}

// ---------------------------------------------------------------------------
// bf16 helpers (256^2 pipeline)
// ---------------------------------------------------------------------------
static __device__ __forceinline__ void readA4(bf16x8 (&a)[4][2],
                                              const char* __restrict__ base,
                                              const int (&off)[4][2]) {
#pragma unroll
  for (int m = 0; m < 4; ++m)
#pragma unroll
    for (int kk = 0; kk < 2; ++kk)
      a[m][kk] = *(const bf16x8*)(base + off[m][kk]);
}
static __device__ __forceinline__ void readB2(bf16x8 (&b)[2][2],
                                              const char* __restrict__ base,
                                              const int (&off)[2][2]) {
#pragma unroll
  for (int n = 0; n < 2; ++n)
#pragma unroll
    for (int kk = 0; kk < 2; ++kk)
      b[n][kk] = *(const bf16x8*)(base + off[n][kk]);
}
static __device__ __forceinline__ void mfmaQ(f32x4 (&aq)[4][2],
                                             const bf16x8 (&a)[4][2],
                                             const bf16x8 (&b)[2][2]) {
#pragma unroll
  for (int m = 0; m < 4; ++m)
#pragma unroll
    for (int n = 0; n < 2; ++n)
#pragma unroll
      for (int kk = 0; kk < 2; ++kk)
        aq[m][n] = __builtin_amdgcn_mfma_f32_16x16x32_bf16(a[m][kk], b[n][kk],
                                                           aq[m][n], 0, 0, 0);
}

// ---------------------------------------------------------------------------
// prep_bm256: M[o,i] = q*scale + min_val + sum_r Ub[o,r]*Vs[i,r]  (bf16 out)
// r6's proven 256x256 bf16 pipeline with K=RANK=512 (nK=8: 3 iters + tail).
// ---------------------------------------------------------------------------
__global__ __launch_bounds__(512, 2) void prep_bm256(
    const unsigned short* __restrict__ Ub, const unsigned short* __restrict__ Vs,
    const int* __restrict__ qq, const float* __restrict__ scale_p,
    const float* __restrict__ minv_p, unsigned short* __restrict__ M) {
  extern __shared__ __align__(128) char smem[];
  const int tid  = threadIdx.x;
  const int wid  = tid >> 6;
  const int lane = tid & 63;
  const int wqm  = wid >> 2;
  const int wqn  = wid & 3;

  // nwg = 256, divisible by 8
  const int swz = (blockIdx.x & 7) * 32 + (blockIdx.x >> 3);
  const int bm = swz >> 4;   // 0..15 over OUT_F
  const int bn = swz & 15;   // 0..15 over IN_F
  const int row0 = bm * 256;
  const int col0 = bn * 256;

  int offA[4][2], offB[2][2];
#pragma unroll
  for (int m = 0; m < 4; ++m)
#pragma unroll
    for (int kk = 0; kk < 2; ++kk) {
      int r = wqm * 64 + m * 16 + (lane & 15);
      int cb = kk * 64 + (lane >> 4) * 16;
      offA[m][kk] = r * 128 + (cb ^ ((r & 7) << 4));
    }
#pragma unroll
  for (int n = 0; n < 2; ++n)
#pragma unroll
    for (int kk = 0; kk < 2; ++kk) {
      int r = wqn * 32 + n * 16 + (lane & 15);
      int cb = kk * 64 + (lane >> 4) * 16;
      offB[n][kk] = r * 128 + (cb ^ ((r & 7) << 4));
    }

  const int sco = (((lane & 7) ^ (lane >> 3)) << 3);
  const int srw = lane >> 3;
  const unsigned short* aP = Ub + (size_t)(row0 + wid * 16 + srw) * RANK + sco;
  const unsigned short* bP = Vs + (size_t)(col0 + wid * 16 + srw) * RANK + sco;
  const unsigned short* aH = aP + (size_t)128 * RANK;
  const unsigned short* bH = bP + (size_t)128 * RANK;
  char* lw = smem + wid * 2048;

  auto STG = [&](const unsigned short* __restrict__ g, char* l) {
    gload_lds16(g, l);
    gload_lds16(g + 8 * RANK, l + 1024);
  };

  f32x4 acc[4][4][2] = {};
  bf16x8 a[4][2], b0[2][2], b1[2][2];

  // prologue: t0 {A0,B0,B1,A1} -> buf0; t1 {A0,B0,B1} -> buf1
  STG(aP,       lw + 0);
  STG(bP,       lw + 32768);
  STG(bH,       lw + 49152);
  STG(aH,       lw + 16384);
  STG(aP + 64,  lw + 65536);
  STG(bP + 64,  lw + 98304);
  STG(bH + 64,  lw + 114688);
  asm volatile("s_waitcnt vmcnt(6)");
  SCHED();
  BARR();

  // main loop: 3 iterations, tiles 0..5
  for (int it = 0; it < 3; ++it) {
    readA4(a, smem, offA);
    readB2(b0, smem + 32768, offB);
    STG(aH + 64, lw + 81920);
    asm volatile("s_waitcnt lgkmcnt(8)");
    BARR(); LGKM0(); SCHED();
    PRIO1(); mfmaQ(acc[0], a, b0); PRIO0(); SCHED(); BARR();

    readB2(b1, smem + 49152, offB);
    STG(aP + 128, lw + 0);
    BARR(); LGKM0(); SCHED();
    PRIO1(); mfmaQ(acc[1], a, b1); PRIO0(); SCHED(); BARR();

    readA4(a, smem + 16384, offA);
    STG(bP + 128, lw + 32768);
    BARR(); LGKM0(); SCHED();
    PRIO1(); mfmaQ(acc[2], a, b1); PRIO0(); SCHED(); BARR();

    STG(bH + 128, lw + 49152);
    asm volatile("s_waitcnt vmcnt(6)");
    SCHED(); BARR();
    PRIO1(); mfmaQ(acc[3], a, b0); PRIO0(); SCHED(); BARR();

    readA4(a, smem + 65536, offA);
    readB2(b0, smem + 98304, offB);
    STG(aH + 128, lw + 16384);
    asm volatile("s_waitcnt lgkmcnt(8)");
    BARR(); LGKM0(); SCHED();
    PRIO1(); mfmaQ(acc[0], a, b0); PRIO0(); SCHED(); BARR();

    readB2(b1, smem + 114688, offB);
    STG(aP + 192, lw + 65536);
    BARR(); LGKM0(); SCHED();
    PRIO1(); mfmaQ(acc[1], a, b1); PRIO0(); SCHED(); BARR();

    readA4(a, smem + 81920, offA);
    STG(bP + 192, lw + 98304);
    BARR(); LGKM0(); SCHED();
    PRIO1(); mfmaQ(acc[2], a, b1); PRIO0(); SCHED(); BARR();

    STG(bH + 192, lw + 114688);
    asm volatile("s_waitcnt vmcnt(6)");
    SCHED(); BARR();
    PRIO1(); mfmaQ(acc[3], a, b0); PRIO0(); SCHED(); BARR();

    aP += 128; bP += 128; aH += 128; bH += 128;
  }

  // peeled tail: tile 6 (buf0), tile 7 (buf1)
  readA4(a, smem, offA);
  readB2(b0, smem + 32768, offB);
  STG(aH + 64, lw + 81920);
  asm volatile("s_waitcnt lgkmcnt(8)");
  BARR(); LGKM0(); SCHED();
  PRIO1(); mfmaQ(acc[0], a, b0); PRIO0(); SCHED(); BARR();

  readB2(b1, smem + 49152, offB);
  BARR(); LGKM0(); SCHED();
  PRIO1(); mfmaQ(acc[1], a, b1); PRIO0(); SCHED(); BARR();

  readA4(a, smem + 16384, offA);
  BARR(); LGKM0(); SCHED();
  PRIO1(); mfmaQ(acc[2], a, b1); PRIO0(); SCHED(); BARR();

  asm volatile("s_waitcnt vmcnt(0)");
  SCHED(); BARR();
  PRIO1(); mfmaQ(acc[3], a, b0); PRIO0(); SCHED(); BARR();

  readA4(a, smem + 65536, offA);
  readB2(b0, smem + 98304, offB);
  BARR(); LGKM0(); SCHED();
  PRIO1(); mfmaQ(acc[0], a, b0); PRIO0(); SCHED(); BARR();

  readB2(b1, smem + 114688, offB);
  BARR(); LGKM0(); SCHED();
  PRIO1(); mfmaQ(acc[1], a, b1); PRIO0(); SCHED(); BARR();

  readA4(a, smem + 81920, offA);
  BARR(); LGKM0(); SCHED();
  PRIO1(); mfmaQ(acc[2], a, b1); PRIO0(); SCHED();
  mfmaQ(acc[3], a, b0);

  // epilogue: add dequantized q, store bf16 M
  const float scale = *scale_p;
  const float minv  = *minv_p;
  const int qm_[4] = {0, 0, 1, 1};
  const int qn_[4] = {0, 1, 1, 0};
#pragma unroll
  for (int q = 0; q < 4; ++q) {
#pragma unroll
    for (int m = 0; m < 4; ++m) {
#pragma unroll
      for (int n = 0; n < 2; ++n) {
        int col = col0 + qn_[q] * 128 + wqn * 32 + n * 16 + (lane & 15);
#pragma unroll
        for (int rr = 0; rr < 4; ++rr) {
          int row = row0 + qm_[q] * 128 + wqm * 64 + m * 16 + (lane >> 4) * 4 + rr;
          float dq = (float)qq[(size_t)row * IN_F + col] * scale + minv;
          M[(size_t)row * IN_F + col] = f2bf(acc[q][m][n][rr] + dq);
        }
      }
    }
  }
}

// ---------------------------------------------------------------------------
// prep_qm: per-output-row i8 quant of M (bf16 -> i8 + sm[o])
// ---------------------------------------------------------------------------
__global__ __launch_bounds__(256) void prep_qm(const unsigned short* __restrict__ M,
                                               char* __restrict__ mi8,
                                               float* __restrict__ sm) {
  __shared__ float red[4];
  const int row = blockIdx.x;
  const int t = threadIdx.x;
  const unsigned short* mr = M + (size_t)row * IN_F;
  float v[16];
  float am = 0.f;
#pragma unroll
  for (int j = 0; j < 2; ++j) {
    short8v h = *(const short8v*)&mr[t * 16 + j * 8];
#pragma unroll
    for (int e = 0; e < 8; ++e) {
      float f = bf2f((unsigned short)h[e]);
      v[j * 8 + e] = f;
      am = fmaxf(am, fabsf(f));
    }
  }
#pragma unroll
  for (int s = 32; s; s >>= 1) am = fmaxf(am, __shfl_xor(am, s));
  if ((t & 63) == 0) red[t >> 6] = am;
  __syncthreads();
  am = fmaxf(fmaxf(red[0], red[1]), fmaxf(red[2], red[3]));
  am = fmaxf(am, 1e-12f);
  const float inv = 127.0f / am;
  i32x4 pk;
#pragma unroll
  for (int j = 0; j < 4; ++j) {
    unsigned p = 0;
#pragma unroll
    for (int e = 0; e < 4; ++e) {
      float qf = rintf(v[j * 4 + e] * inv);
      qf = fminf(fmaxf(qf, -127.f), 127.f);
      p |= ((unsigned)((int)qf & 0xFF)) << (8 * e);
    }
    pk[j] = (int)p;
  }
  *(i32x4*)&mi8[(size_t)row * IN_F + t * 16] = pk;
  if (t == 0) sm[row] = am * (1.0f / 127.0f);
}

// ---------------------------------------------------------------------------
// i8 helpers
// ---------------------------------------------------------------------------
static __device__ __forceinline__ void readA4i(i32x4 (&a)[4][2],
                                               const char* __restrict__ base,
                                               const int (&off)[4][2]) {
#pragma unroll
  for (int m = 0; m < 4; ++m)
#pragma unroll
    for (int kk = 0; kk < 2; ++kk)
      a[m][kk] = *(const i32x4*)(base + off[m][kk]);
}
static __device__ __forceinline__ void readB2i(i32x4 (&b)[2][2],
                                               const char* __restrict__ base,
                                               const int (&off)[2][2]) {
#pragma unroll
  for (int n = 0; n < 2; ++n)
#pragma unroll
    for (int kk = 0; kk < 2; ++kk)
      b[n][kk] = *(const i32x4*)(base + off[n][kk]);
}
static __device__ __forceinline__ void mfmaQi(i32x4 (&aq)[4][2],
                                              const i32x4 (&a)[4][2],
                                              const i32x4 (&b)[2][2]) {
#pragma unroll
  for (int m = 0; m < 4; ++m)
#pragma unroll
    for (int n = 0; n < 2; ++n)
#pragma unroll
      for (int kk = 0; kk < 2; ++kk)
        aq[m][n] = __builtin_amdgcn_mfma_i32_16x16x64_i8(a[m][kk], b[n][kk],
                                                         aq[m][n], 0, 0, 0);
}

// ---------------------------------------------------------------------------
// gemm256_i8 (round-7 schedule, verbatim): 4 phases/K-tile, counted vmcnt(6).
// ---------------------------------------------------------------------------
__global__ __launch_bounds__(512, 2) void gemm256_i8(
    const char* __restrict__ xi8, const char* __restrict__ mi8,
    const float* __restrict__ sx, const float* __restrict__ sm,
    float* __restrict__ out) {
  extern __shared__ __align__(128) char smem[];
  const int tid  = threadIdx.x;
  const int wid  = tid >> 6;
  const int lane = tid & 63;
  const int wqm  = wid >> 2;
  const int wqn  = wid & 3;

  const int swz = (blockIdx.x & 7) * 64 + (blockIdx.x >> 3);
  const int bm = swz >> 4;
  const int bn = swz & 15;
  const int row0 = bm * 256;
  const int col0 = bn * 256;

  int offA[4][2], offB[2][2];
#pragma unroll
  for (int m = 0; m < 4; ++m)
#pragma unroll
    for (int kk = 0; kk < 2; ++kk) {
      int r = wqm * 64 + m * 16 + (lane & 15);
      int cb = kk * 64 + (lane >> 4) * 16;
      offA[m][kk] = r * 128 + (cb ^ ((r & 7) << 4));
    }
#pragma unroll
  for (int n = 0; n < 2; ++n)
#pragma unroll
    for (int kk = 0; kk < 2; ++kk) {
      int r = wqn * 32 + n * 16 + (lane & 15);
      int cb = kk * 64 + (lane >> 4) * 16;
      offB[n][kk] = r * 128 + (cb ^ ((r & 7) << 4));
    }

  const int sco = (((lane & 7) ^ (lane >> 3)) << 4);
  const int srw = lane >> 3;
  const char* aP = xi8 + (size_t)(row0 + wid * 16 + srw) * IN_F + sco;
  const char* bP = mi8 + (size_t)(col0 + wid * 16 + srw) * IN_F + sco;
  const char* aH = aP + (size_t)128 * IN_F;
  const char* bH = bP + (size_t)128 * IN_F;
  char* lw = smem + wid * 2048;

  auto STG = [&](const char* __restrict__ g, char* l) {
    gload_lds16(g, l);
    gload_lds16(g + 8 * IN_F, l + 1024);
  };

  i32x4 acc[4][4][2] = {};
  i32x4 a[4][2], b0[2][2], b1[2][2];

  STG(aP,        lw + 0);
  STG(bP,        lw + 32768);
  STG(bH,        lw + 49152);
  STG(aH,        lw + 16384);
  STG(aP + 128,  lw + 65536);
  STG(bP + 128,  lw + 98304);
  STG(bH + 128,  lw + 114688);
  asm volatile("s_waitcnt vmcnt(6)");
  SCHED();
  BARR();

  for (int it = 0; it < 15; ++it) {
    readA4i(a, smem, offA);
    readB2i(b0, smem + 32768, offB);
    STG(aH + 128, lw + 81920);
    asm volatile("s_waitcnt lgkmcnt(8)");
    BARR(); LGKM0(); SCHED();
    PRIO1(); mfmaQi(acc[0], a, b0); PRIO0(); SCHED(); BARR();

    readB2i(b1, smem + 49152, offB);
    STG(aP + 256, lw + 0);
    BARR(); LGKM0(); SCHED();
    PRIO1(); mfmaQi(acc[1], a, b1); PRIO0(); SCHED(); BARR();

    readA4i(a, smem + 16384, offA);
    STG(bP + 256, lw + 32768);
    BARR(); LGKM0(); SCHED();
    PRIO1(); mfmaQi(acc[2], a, b1); PRIO0(); SCHED(); BARR();

    STG(bH + 256, lw + 49152);
    asm volatile("s_waitcnt vmcnt(6)");
    SCHED(); BARR();
    PRIO1(); mfmaQi(acc[3], a, b0); PRIO0(); SCHED(); BARR();

    readA4i(a, smem + 65536, offA);
    readB2i(b0, smem + 98304, offB);
    STG(aH + 256, lw + 16384);
    asm volatile("s_waitcnt lgkmcnt(8)");
    BARR(); LGKM0(); SCHED();
    PRIO1(); mfmaQi(acc[0], a, b0); PRIO0(); SCHED(); BARR();

    readB2i(b1, smem + 114688, offB);
    STG(aP + 384, lw + 65536);
    BARR(); LGKM0(); SCHED();
    PRIO1(); mfmaQi(acc[1], a, b1); PRIO0(); SCHED(); BARR();

    readA4i(a, smem + 81920, offA);
    STG(bP + 384, lw + 98304);
    BARR(); LGKM0(); SCHED();
    PRIO1(); mfmaQi(acc[2], a, b1); PRIO0(); SCHED(); BARR();

    STG(bH + 384, lw + 114688);
    asm volatile("s_waitcnt vmcnt(6)");
    SCHED(); BARR();
    PRIO1(); mfmaQi(acc[3], a, b0); PRIO0(); SCHED(); BARR();

    aP += 256; bP += 256; aH += 256; bH += 256;
  }

  readA4i(a, smem, offA);
  readB2i(b0, smem + 32768, offB);
  STG(aH + 128, lw + 81920);
  asm volatile("s_waitcnt lgkmcnt(8)");
  BARR(); LGKM0(); SCHED();
  PRIO1(); mfmaQi(acc[0], a, b0); PRIO0(); SCHED(); BARR();

  readB2i(b1, smem + 49152, offB);
  BARR(); LGKM0(); SCHED();
  PRIO1(); mfmaQi(acc[1], a, b1); PRIO0(); SCHED(); BARR();

  readA4i(a, smem + 16384, offA);
  BARR(); LGKM0(); SCHED();
  PRIO1(); mfmaQi(acc[2], a, b1); PRIO0(); SCHED(); BARR();

  asm volatile("s_waitcnt vmcnt(0)");
  SCHED(); BARR();
  PRIO1(); mfmaQi(acc[3], a, b0); PRIO0(); SCHED(); BARR();

  readA4i(a, smem + 65536, offA);
  readB2i(b0, smem + 98304, offB);
  BARR(); LGKM0(); SCHED();
  PRIO1(); mfmaQi(acc[0], a, b0); PRIO0(); SCHED(); BARR();

  readB2i(b1, smem + 114688, offB);
  BARR(); LGKM0(); SCHED();
  PRIO1(); mfmaQi(acc[1], a, b1); PRIO0(); SCHED(); BARR();

  readA4i(a, smem + 81920, offA);
  BARR(); LGKM0(); SCHED();
  PRIO1(); mfmaQi(acc[2], a, b1); PRIO0(); SCHED();
  mfmaQi(acc[3], a, b0);

  const int qm_[4] = {0, 0, 1, 1};
  const int qn_[4] = {0, 1, 1, 0};
#pragma unroll
  for (int q = 0; q < 4; ++q) {
#pragma unroll
    for (int m = 0; m < 4; ++m) {
#pragma unroll
      for (int n = 0; n < 2; ++n) {
        int col = col0 + qn_[q] * 128 + wqn * 32 + n * 16 + (lane & 15);
        float smv = sm[col];
#pragma unroll
        for (int rr = 0; rr < 4; ++rr) {
          int row = row0 + qm_[q] * 128 + wqm * 64 + m * 16 + (lane >> 4) * 4 + rr;
          out[(size_t)row * OUT_F + col] =
              (float)acc[q][m][n][rr] * sx[row] * smv;
        }
      }
    }
  }
}

// ---------------------------------------------------------------------------
// Fallback path kernels (ws too small): old 128^2 build_m + f32-A bf16 gemm.
// ---------------------------------------------------------------------------
__global__ __launch_bounds__(256) void prep_bm(
    const float* __restrict__ U, const float* __restrict__ V,
    const float* __restrict__ S, const int* __restrict__ q,
    const float* __restrict__ scale_p, const float* __restrict__ minv_p,
    unsigned short* __restrict__ M) {
  __shared__ unsigned short lA[128 * 64];
  __shared__ unsigned short lB[128 * 64];
  const int tid  = threadIdx.x;
  const int wid  = tid >> 6;
  const int lane = tid & 63;
  const int bm = blockIdx.x >> 5;
  const int bn = blockIdx.x & 31;
  const int wm = (wid >> 1) * 64;
  const int wn = (wid & 1) * 64;
  f32x4 acc[4][4] = {};
  const int sr = tid >> 4;
  const int sc = (tid & 15) * 4;
  for (int k0 = 0; k0 < RANK; k0 += 64) {
    __syncthreads();
#pragma unroll
    for (int p = 0; p < 8; ++p) {
      int row = p * 16 + sr;
      f32x4 uv = *(const f32x4*)&U[(size_t)(bm * 128 + row) * RANK + k0 + sc];
      short4v pa;
      pa.x = (short)f2bf(uv.x); pa.y = (short)f2bf(uv.y);
      pa.z = (short)f2bf(uv.z); pa.w = (short)f2bf(uv.w);
      *(short4v*)&lA[row * 64 + sc] = pa;
      f32x4 vv = *(const f32x4*)&V[(size_t)(bn * 128 + row) * RANK + k0 + sc];
      f32x4 sv = *(const f32x4*)&S[k0 + sc];
      short4v pb;
      pb.x = (short)f2bf(vv.x * sv.x); pb.y = (short)f2bf(vv.y * sv.y);
      pb.z = (short)f2bf(vv.z * sv.z); pb.w = (short)f2bf(vv.w * sv.w);
      *(short4v*)&lB[row * 64 + sc] = pb;
    }
    __syncthreads();
#pragma unroll
    for (int kk = 0; kk < 2; ++kk) {
      bf16x8 af[4], bfr[4];
#pragma unroll
      for (int m = 0; m < 4; ++m)
        af[m] = *(const bf16x8*)&lA[(wm + m * 16 + (lane & 15)) * 64 + kk * 32 + (lane >> 4) * 8];
#pragma unroll
      for (int n = 0; n < 4; ++n)
        bfr[n] = *(const bf16x8*)&lB[(wn + n * 16 + (lane & 15)) * 64 + kk * 32 + (lane >> 4) * 8];
#pragma unroll
      for (int m = 0; m < 4; ++m)
#pragma unroll
        for (int n = 0; n < 4; ++n)
          acc[m][n] = __builtin_amdgcn_mfma_f32_16x16x32_bf16(af[m], bfr[n], acc[m][n], 0, 0, 0);
    }
  }
  const float scale = *scale_p;
  const float minv  = *minv_p;
  const int o0 = bm * 128 + wm;
  const int i0 = bn * 128 + wn;
#pragma unroll
  for (int m = 0; m < 4; ++m)
#pragma unroll
    for (int n = 0; n < 4; ++n) {
      int col = i0 + n * 16 + (lane & 15);
#pragma unroll
      for (int rr = 0; rr < 4; ++rr) {
        int row = o0 + m * 16 + (lane >> 4) * 4 + rr;
        float dq = (float)q[(size_t)row * IN_F + col] * scale + minv;
        M[(size_t)row * IN_F + col] = f2bf(acc[m][n][rr] + dq);
      }
    }
}

__global__ __launch_bounds__(256) void gemm_main_f(const float* __restrict__ xf,
                                                   const unsigned short* __restrict__ Mw,
                                                   float* __restrict__ out) {
  __shared__ unsigned short lA[128 * 64];
  __shared__ unsigned short lB[128 * 64];
  const int tid  = threadIdx.x;
  const int wid  = tid >> 6;
  const int lane = tid & 63;
  const int nwg = gridDim.x;
  const int cpx = nwg >> 3;
  const int swz = (blockIdx.x & 7) * cpx + (blockIdx.x >> 3);
  const int bm = swz >> 5;
  const int bn = swz & 31;
  const int wm = (wid >> 1) * 64;
  const int wn = (wid & 1) * 64;
  const int row0 = bm * 128;
  const int col0 = bn * 128;
  f32x4 acc[4][4] = {};
  for (int k0 = 0; k0 < IN_F; k0 += 64) {
    __syncthreads();
    const int sr = tid >> 4;
    const int sc = (tid & 15) * 4;
#pragma unroll
    for (int p = 0; p < 8; ++p) {
      int row = p * 16 + sr;
      f32x4 v = *(const f32x4*)&xf[(size_t)(row0 + row) * IN_F + k0 + sc];
      short4v pa;
      pa.x = (short)f2bf(v.x); pa.y = (short)f2bf(v.y);
      pa.z = (short)f2bf(v.z); pa.w = (short)f2bf(v.w);
      *(short4v*)&lA[row * 64 + sc] = pa;
    }
#pragma unroll
    for (int j = 0; j < 4; ++j) {
      int rbase = (wid * 4 + j) * 8;
      const unsigned short* src =
          &Mw[(size_t)(col0 + rbase + (lane >> 3)) * IN_F + k0 + (lane & 7) * 8];
      gload_lds16(src, &lB[rbase * 64]);
    }
    __syncthreads();
#pragma unroll
    for (int kk = 0; kk < 2; ++kk) {
      bf16x8 af[4], bfr[4];
#pragma unroll
      for (int m = 0; m < 4; ++m)
        af[m] = *(const bf16x8*)&lA[(wm + m * 16 + (lane & 15)) * 64 + kk * 32 + (lane >> 4) * 8];
#pragma unroll
      for (int n = 0; n < 4; ++n)
        bfr[n] = *(const bf16x8*)&lB[(wn + n * 16 + (lane & 15)) * 64 + kk * 32 + (lane >> 4) * 8];
#pragma unroll
      for (int m = 0; m < 4; ++m)
#pragma unroll
        for (int n = 0; n < 4; ++n)
          acc[m][n] = __builtin_amdgcn_mfma_f32_16x16x32_bf16(af[m], bfr[n], acc[m][n], 0, 0, 0);
    }
  }
#pragma unroll
  for (int m = 0; m < 4; ++m)
#pragma unroll
    for (int n = 0; n < 4; ++n) {
      int col = col0 + wn + n * 16 + (lane & 15);
#pragma unroll
      for (int rr = 0; rr < 4; ++rr) {
        int row = row0 + wm + m * 16 + (lane >> 4) * 4 + rr;
        out[(size_t)row * OUT_F + col] = acc[m][n][rr];
      }
    }
}

// ---------------------------------------------------------------------------
extern "C" void kernel_launch(void* const* d_in, const int* in_sizes, int n_in,
                              void* d_out, int out_size, void* d_ws, size_t ws_size,
                              hipStream_t stream) {
  const float* x      = (const float*)d_in[0];
  const int*   q      = (const int*)d_in[1];
  const float* scale  = (const float*)d_in[2];
  const float* minv   = (const float*)d_in[3];
  const float* U      = (const float*)d_in[4];
  const float* S      = (const float*)d_in[5];
  const float* V      = (const float*)d_in[6];
  float* out = (float*)d_out;

  const size_t MB32 = 33554432ull;
  unsigned short* Mw = (unsigned short*)d_ws;                         // 32 MB
  char*  xi8 = (char*)d_ws + MB32;                                    // 32 MB
  char*  mi8 = (char*)d_ws + 2 * MB32;                                // 16 MB
  float* sx  = (float*)((char*)d_ws + 2 * MB32 + 16777216);           // 32 KB
  float* sm  = (float*)((char*)d_ws + 2 * MB32 + 16777216 + 32768);   // 16 KB
  unsigned short* Ub = (unsigned short*)((char*)d_ws + 2 * MB32 + 16777216 + 65536);  // 4 MB
  unsigned short* Vs = Ub + (size_t)OUT_F * RANK;                     // 4 MB
  const size_t need = 2 * MB32 + 16777216 + 65536 + 2 * 4194304;

  if (ws_size >= need) {
    (void)hipFuncSetAttribute((const void*)gemm256_i8,
                              hipFuncAttributeMaxDynamicSharedMemorySize,
                              131072);
    (void)hipFuncSetAttribute((const void*)prep_bm256,
                              hipFuncAttributeMaxDynamicSharedMemorySize,
                              131072);
    prep_conv<<<dim3(8704), dim3(256), 0, stream>>>(x, xi8, sx, U, V, S, Ub, Vs);
    prep_bm256<<<dim3(256), dim3(512), 131072, stream>>>(Ub, Vs, q, scale,
                                                         minv, Mw);
    prep_qm<<<dim3(4096), dim3(256), 0, stream>>>(Mw, mi8, sm);
    gemm256_i8<<<dim3(512), dim3(512), 131072, stream>>>(xi8, mi8, sx, sm, out);
  } else {
    prep_bm<<<dim3(1024), dim3(256), 0, stream>>>(U, V, S, q, scale, minv, Mw);
    gemm_main_f<<<dim3(2048), dim3(256), 0, stream>>>(x, Mw, out);
  }
}